// Round 7
// baseline (82.217 us; speedup 1.0000x reference)
//
#include <hip/hip_runtime.h>

// Parzen-window histogram density, B=2, N=2, NUM_BINS=16, RADIUS=2, K=20.
//
// Reference semantics (by elimination over R1-R6): XLA-jitted f32, source
// association order, with the division strength-reduced by XLA's algebraic
// simplifier:  divide(a, broadcast(bw_safe)) -> a * (1 / bw_safe).
// So bin_pos = fl32( a * cr32(1/bws) )  -- TWO roundings, not one cr divide.
// Every voxel sits on the floor knife edge (bin_pos ~ 2 and 18), so we
// reproduce both roundings EXACTLY and fast-math-proof:
//  * r = cr32(1/bws): f64 guide + midpoint adjustment. Midpoints
//    mp=(u+next)/2 have 25-bit significands; mp*b is exact in f64 (25x24).
//    Ties (1/b == midpoint) are impossible unless b is a power of 2 (then
//    1/b is exact anyway).
//  * q = fl32(a*r): 24x24-bit product is exact in f64; single cast = cr32.
// All other chain ops (sub, mul-by-pow2, max) are single correctly-rounded
// f32 ops on both sides. Weights/normalization are continuous -> f32 fine;
// comparison is bf16-quantized with a 2% threshold.

__device__ __forceinline__ float bsplinef(float d) {
    float ad = fabsf(d);
    if (ad >= 2.0f) return 0.0f;
    float ad2 = ad * ad;
    if (ad < 1.0f) return (3.0f * ad2 * ad - 6.0f * ad2 + 4.0f) * (1.0f / 6.0f);
    float t = 2.0f - ad;
    return (t * t * t) * (1.0f / 6.0f);
}

// exact correctly-rounded f32 reciprocal of b > 0 (fast-math-proof)
__device__ __forceinline__ float recip_cr32(float b) {
    double bd = (double)b;
    float u = (float)(1.0 / bd);              // within 1 ulp of cr32
    unsigned ui = __float_as_uint(u);
    float un = __uint_as_float(ui + 1);       // neighbor up
    float ud = __uint_as_float(ui - 1);       // neighbor down
    double mp = 0.5 * ((double)u + (double)un);   // exact midpoints
    double mm = 0.5 * ((double)u + (double)ud);
    if (mp * bd <= 1.0) u = un;               // 1/b >= mp  -> round up
    else if (mm * bd > 1.0) u = ud;           // 1/b <  mm  -> round down
    return u;
}

// exact fl32(a * r) via exact f64 product (24x24 bits) + single cast
__device__ __forceinline__ float mul_cr32(float a, float r) {
    return (float)((double)a * (double)r);
}

__device__ __forceinline__ void parzen_pair(float x0, float x1, float m0, float m1,
                                            float& o0, float& o1) {
    float mx = fmaxf(x0, x1);
    float mn = fminf(x0, x1);
    float c   = mx - mn;               // single cr32 sub
    float bw  = c * 0.0625f;           // exact (/16)
    float b2  = bw + bw;               // exact
    float pad = mn - b2;               // single cr32 sub
    float bws = fmaxf(bw, 1e-8f);
    float r   = recip_cr32(bws);       // cr32(1/bws)
    float a0  = x0 - pad;              // single cr32 sub
    float a1  = x1 - pad;
    float q0  = mul_cr32(a0, r);       // bin_pos = fl32(a * r)
    float q1  = mul_cr32(a1, r);

    int fq0 = (int)fminf(fmaxf(floorf(q0), 0.0f), 20.0f);
    int fq1 = (int)fminf(fmaxf(floorf(q1), 0.0f), 20.0f);
    int base0 = min(max(fq0, 2), 17) - 1;   // hist window {base..base+3}
    int base1 = min(max(fq1, 2), 17) - 1;
    int i0 = min(max(fq0, 0), 19);          // gather bin per image
    int i1 = min(max(fq1, 0), 19);

    float w0[4], w1[4];
#pragma unroll
    for (int k = 0; k < 4; ++k) w0[k] = bsplinef(q0 - (float)(base0 + k));
#pragma unroll
    for (int k = 0; k < 4; ++k) w1[k] = bsplinef(q1 - (float)(base1 + k));

    // numerator: hist value at each image's gather bin
    float h0 = 0.0f, h1 = 0.0f;
    {
        int k = i0 - base0;
        if (k >= 0 && k < 4) h0 += w0[k];
        k = i0 - base1;
        if (k >= 0 && k < 4) h0 += w1[k];
        k = i1 - base0;
        if (k >= 0 && k < 4) h1 += w0[k];
        k = i1 - base1;
        if (k >= 0 && k < 4) h1 += w1[k];
    }

    // denominator: total histogram mass, ascending-k order
    float denom = 0.0f;
    int d = base1 - base0;
    if (d >= 4 || d <= -4) {            // disjoint windows (generic case)
        const float* wl = (d > 0) ? w0 : w1;
        const float* wh = (d > 0) ? w1 : w0;
        denom = wl[0] + wl[1] + wl[2] + wl[3];
        denom += wh[0] + wh[1] + wh[2] + wh[3];
    } else {                            // overlapping (bw ~ 0)
        int lo = (d > 0) ? base0 : base1;
        int hi = ((d > 0) ? base1 : base0) + 3;
        for (int k = lo; k <= hi; ++k) {
            float cc = 0.0f;
            int k0 = k - base0, k1 = k - base1;
            if (k0 >= 0 && k0 < 4) cc += w0[k0];
            if (k1 >= 0 && k1 < 4) cc += w1[k1];
            denom += cc;
        }
    }

    float dc = fmaxf(denom, 1e-8f);
    o0 = (m0 != 0.0f) ? (h0 / dc) : 0.0f;
    o1 = (m1 != 0.0f) ? (h1 / dc) : 0.0f;
}

__global__ __launch_bounds__(256) void parzen_kernel(
    const float* __restrict__ img, const float* __restrict__ mask,
    float* __restrict__ out, int V) {
    const int V4 = V >> 2;
    int t = blockIdx.x * blockDim.x + threadIdx.x;
    if (t >= 2 * V4) return;               // B = 2
    int b = (t >= V4) ? 1 : 0;
    int v = (t - b * V4) << 2;

    size_t off0 = (size_t)(b * 2 + 0) * (size_t)V + (size_t)v;  // n = 0
    size_t off1 = (size_t)(b * 2 + 1) * (size_t)V + (size_t)v;  // n = 1

    const float4 X0 = *reinterpret_cast<const float4*>(img  + off0);
    const float4 X1 = *reinterpret_cast<const float4*>(img  + off1);
    const float4 M0 = *reinterpret_cast<const float4*>(mask + off0);
    const float4 M1 = *reinterpret_cast<const float4*>(mask + off1);

    float4 O0, O1;
    parzen_pair(X0.x, X1.x, M0.x, M1.x, O0.x, O1.x);
    parzen_pair(X0.y, X1.y, M0.y, M1.y, O0.y, O1.y);
    parzen_pair(X0.z, X1.z, M0.z, M1.z, O0.z, O1.z);
    parzen_pair(X0.w, X1.w, M0.w, M1.w, O0.w, O1.w);

    *reinterpret_cast<float4*>(out + off0) = O0;
    *reinterpret_cast<float4*>(out + off1) = O1;
}

extern "C" void kernel_launch(void* const* d_in, const int* in_sizes, int n_in,
                              void* d_out, int out_size, void* d_ws, size_t ws_size,
                              hipStream_t stream) {
    const float* img  = (const float*)d_in[0];   // [2,2,1,96,96,96] f32
    const float* mask = (const float*)d_in[1];   // [2,2,96,96,96] f32
    float* out = (float*)d_out;                  // [2,2,96,96,96] f32

    int total = in_sizes[0];      // 4*V
    int V = total / 4;            // 884736 (divisible by 4)
    int threads = 2 * (V >> 2);
    int block = 256;
    int grid = (threads + block - 1) / block;
    parzen_kernel<<<grid, block, 0, stream>>>(img, mask, out, V);
}

// Round 8
// 80.695 us; speedup vs baseline: 1.0189x; 1.0189x over previous
//
#include <hip/hip_runtime.h>

// Parzen-window histogram density, B=2, N=2, NUM_BINS=16, RADIUS=2, K=20.
//
// Reference semantics (verified absmax=0.0 in R7): XLA-jitted f32, source
// association order, division strength-reduced to reciprocal-multiply:
//   bin_pos = fl32( a * cr32(1/bw_safe) ).
// Floor path must stay bit-exact (every voxel sits on the 2/18 knife edge):
//  * r = cr32(1/bws): v_rcp_f32 guide + one f64-fma Newton step (err ~2^-45)
//    + exact midpoint fixup (midpoint*b exact in f64: 25x24 bits).
//  * q = a * r: single native f32 mul (correctly rounded; sub-then-mul can't
//    contract, q is multi-use so it stays materialized).
// Continuous parts (weights, denominator, final divide) tolerate a few f32
// ulps: comparison is bf16-quantized with 2% threshold (1 bf16 ulp = 0.0026
// at 0.33 < 0.0067). So: denominator sum order is free, rcp-mul normalize ok.
//
// Perf: R7's 82us came from scratch (runtime-indexed local arrays + pointer
// select on locals defeated SROA) + f64 division. This version is fully
// branchless with constant-index unrolls -> zero scratch, no f64 div.

__device__ __forceinline__ float bsplinef(float d) {
    float ad = fabsf(d);
    float ad2 = ad * ad;
    float wi = (3.0f * ad2 * ad - 6.0f * ad2 + 4.0f) * (1.0f / 6.0f);
    float t = 2.0f - ad;
    float wo = (t * t * t) * (1.0f / 6.0f);
    float w = ad < 1.0f ? wi : wo;
    return ad < 2.0f ? w : 0.0f;
}

// exact correctly-rounded f32 reciprocal of b > 0 (no f64 division)
__device__ __forceinline__ float recip_cr32(float b) {
    double bd = (double)b;
    float u = __builtin_amdgcn_rcpf(b);           // within 1 ulp
    double ud = (double)u;
    double t = fma(-bd, ud, 1.0);                 // residual
    double g = fma(ud, t, ud);                    // ~2^-45 rel err
    float v = (float)g;                           // cr32 or 1 step off
    unsigned vi = __float_as_uint(v);
    float vn = __uint_as_float(vi + 1);
    float vd = __uint_as_float(vi - 1);
    double mp = 0.5 * ((double)v + (double)vn);   // exact midpoints
    double mm = 0.5 * ((double)v + (double)vd);
    if (mp * bd <= 1.0) v = vn;                   // true 1/b >= mp -> up
    else if (mm * bd > 1.0) v = vd;               // true 1/b <  mm -> down
    return v;
}

__device__ __forceinline__ void parzen_pair(float x0, float x1, float m0, float m1,
                                            float& o0, float& o1) {
    float mx = fmaxf(x0, x1);
    float mn = fminf(x0, x1);
    float c   = mx - mn;               // single cr32 sub
    float bw  = c * 0.0625f;           // exact (/16)
    float b2  = bw + bw;               // exact
    float pad = mn - b2;               // single cr32 sub
    float bws = fmaxf(bw, 1e-8f);
    float r   = recip_cr32(bws);       // cr32(1/bws)
    float a0  = x0 - pad;              // single cr32 sub
    float a1  = x1 - pad;
    float q0  = a0 * r;                // bin_pos = fl32(a*r), single mul
    float q1  = a1 * r;

    int fq0 = (int)fminf(fmaxf(floorf(q0), 0.0f), 20.0f);
    int fq1 = (int)fminf(fmaxf(floorf(q1), 0.0f), 20.0f);
    int base0 = min(max(fq0, 2), 17) - 1;   // hist window {base..base+3}
    int base1 = min(max(fq1, 2), 17) - 1;
    int i0 = min(fq0, 19);                  // gather bin per image (fq >= 0)
    int i1 = min(fq1, 19);

    float h0 = 0.0f, h1 = 0.0f, denom = 0.0f;
#pragma unroll
    for (int k = 0; k < 4; ++k) {
        float wa = bsplinef(q0 - (float)(base0 + k));
        float wb = bsplinef(q1 - (float)(base1 + k));
        denom += wa;
        denom += wb;
        h0 += (base0 + k == i0) ? wa : 0.0f;
        h0 += (base1 + k == i0) ? wb : 0.0f;
        h1 += (base0 + k == i1) ? wa : 0.0f;
        h1 += (base1 + k == i1) ? wb : 0.0f;
    }

    float dc = fmaxf(denom, 1e-8f);
    float rd = __builtin_amdgcn_rcpf(dc);   // 1 ulp; bf16-safe
    o0 = (m0 != 0.0f) ? (h0 * rd) : 0.0f;
    o1 = (m1 != 0.0f) ? (h1 * rd) : 0.0f;
}

__global__ __launch_bounds__(256) void parzen_kernel(
    const float* __restrict__ img, const float* __restrict__ mask,
    float* __restrict__ out, int V) {
    const int V4 = V >> 2;
    int t = blockIdx.x * blockDim.x + threadIdx.x;
    if (t >= 2 * V4) return;               // B = 2
    int b = (t >= V4) ? 1 : 0;
    int v = (t - b * V4) << 2;

    size_t off0 = (size_t)(b * 2 + 0) * (size_t)V + (size_t)v;  // n = 0
    size_t off1 = (size_t)(b * 2 + 1) * (size_t)V + (size_t)v;  // n = 1

    const float4 X0 = *reinterpret_cast<const float4*>(img  + off0);
    const float4 X1 = *reinterpret_cast<const float4*>(img  + off1);
    const float4 M0 = *reinterpret_cast<const float4*>(mask + off0);
    const float4 M1 = *reinterpret_cast<const float4*>(mask + off1);

    float4 O0, O1;
    parzen_pair(X0.x, X1.x, M0.x, M1.x, O0.x, O1.x);
    parzen_pair(X0.y, X1.y, M0.y, M1.y, O0.y, O1.y);
    parzen_pair(X0.z, X1.z, M0.z, M1.z, O0.z, O1.z);
    parzen_pair(X0.w, X1.w, M0.w, M1.w, O0.w, O1.w);

    *reinterpret_cast<float4*>(out + off0) = O0;
    *reinterpret_cast<float4*>(out + off1) = O1;
}

extern "C" void kernel_launch(void* const* d_in, const int* in_sizes, int n_in,
                              void* d_out, int out_size, void* d_ws, size_t ws_size,
                              hipStream_t stream) {
    const float* img  = (const float*)d_in[0];   // [2,2,1,96,96,96] f32
    const float* mask = (const float*)d_in[1];   // [2,2,96,96,96] f32
    float* out = (float*)d_out;                  // [2,2,96,96,96] f32

    int total = in_sizes[0];      // 4*V
    int V = total / 4;            // 884736 (divisible by 4)
    int threads = 2 * (V >> 2);
    int block = 256;
    int grid = (threads + block - 1) / block;
    parzen_kernel<<<grid, block, 0, stream>>>(img, mask, out, V);
}

// Round 12
// 77.457 us; speedup vs baseline: 1.0614x; 1.0418x over previous
//
#include <hip/hip_runtime.h>

// Parzen-window histogram density, B=2, N=2, NUM_BINS=16, RADIUS=2, K=20.
//
// Reference semantics (verified absmax=0.0 in R7/R8): XLA-jitted f32, source
// association order, division strength-reduced to reciprocal-multiply:
//   bin_pos = fl32( a * cr32(1/bw_safe) ).
// Floor path BIT-EXACT (knife edge at 2/18 on every voxel):
//  * r = cr32(1/bws): v_rcp_f32 + f64-fma Newton + exact midpoint fixup.
//  * q = a * r: single native f32 mul (correctly rounded).
// Weights MUST use the per-tap piecewise B-spline (NOT the factorized
// basis): near-degenerate voxels (|x0-x1| ~ 1e-7, |mn| ~ 1) give clipped
// fq with frac offsets up to +-2 outside [0,1], where the factorized
// polynomial extrapolates garbage (R11 failure, absmax 0.152) while the
// piecewise form with its |d|>=2 -> 0 branch matches the reference
// exactly (R8: absmax 0.0).

typedef float f32x4 __attribute__((ext_vector_type(4)));

__device__ __forceinline__ float bsplinef(float d) {
    float ad = fabsf(d);
    float ad2 = ad * ad;
    float wi = (3.0f * ad2 * ad - 6.0f * ad2 + 4.0f) * (1.0f / 6.0f);
    float t = 2.0f - ad;
    float wo = (t * t * t) * (1.0f / 6.0f);
    float w = ad < 1.0f ? wi : wo;
    return ad < 2.0f ? w : 0.0f;
}

// exact correctly-rounded f32 reciprocal of b > 0 (no f64 division)
__device__ __forceinline__ float recip_cr32(float b) {
    double bd = (double)b;
    float u = __builtin_amdgcn_rcpf(b);           // within 1 ulp
    double ud = (double)u;
    double t = fma(-bd, ud, 1.0);                 // residual
    double g = fma(ud, t, ud);                    // ~2^-45 rel err
    float v = (float)g;                           // cr32 or one step off
    unsigned vi = __float_as_uint(v);
    float vn = __uint_as_float(vi + 1);
    float vd = __uint_as_float(vi - 1);
    double mp = 0.5 * ((double)v + (double)vn);   // exact midpoints
    double mm = 0.5 * ((double)v + (double)vd);
    if (mp * bd <= 1.0) v = vn;                   // true 1/b >= mp -> up
    else if (mm * bd > 1.0) v = vd;               // true 1/b <  mm -> down
    return v;
}

__device__ __forceinline__ void parzen_pair(float x0, float x1, float m0, float m1,
                                            float& o0, float& o1) {
    float mx = fmaxf(x0, x1);
    float mn = fminf(x0, x1);
    float c   = mx - mn;               // single cr32 sub
    float bw  = c * 0.0625f;           // exact (/16)
    float b2  = bw + bw;               // exact
    float pad = mn - b2;               // single cr32 sub
    float bws = fmaxf(bw, 1e-8f);
    float r   = recip_cr32(bws);       // cr32(1/bws)
    float a0  = x0 - pad;              // single cr32 sub
    float a1  = x1 - pad;
    float q0  = a0 * r;                // bin_pos = fl32(a*r)
    float q1  = a1 * r;

    int fq0 = (int)fminf(fmaxf(floorf(q0), 0.0f), 20.0f);
    int fq1 = (int)fminf(fmaxf(floorf(q1), 0.0f), 20.0f);
    int base0 = min(max(fq0, 2), 17) - 1;   // hist window {base..base+3}
    int base1 = min(max(fq1, 2), 17) - 1;
    int i0 = min(fq0, 19);                  // gather bin per image
    int i1 = min(fq1, 19);

    float h0 = 0.0f, h1 = 0.0f, denom = 0.0f;
#pragma unroll
    for (int k = 0; k < 4; ++k) {           // per-tap piecewise eval (exact)
        float wa = bsplinef(q0 - (float)(base0 + k));
        float wb = bsplinef(q1 - (float)(base1 + k));
        denom += wa;
        denom += wb;
        h0 += (base0 + k == i0) ? wa : 0.0f;
        h0 += (base1 + k == i0) ? wb : 0.0f;
        h1 += (base0 + k == i1) ? wa : 0.0f;
        h1 += (base1 + k == i1) ? wb : 0.0f;
    }

    float dc = fmaxf(denom, 1e-8f);
    float rd = __builtin_amdgcn_rcpf(dc);   // 1 ulp; bf16-safe
    o0 = (m0 != 0.0f) ? (h0 * rd) : 0.0f;
    o1 = (m1 != 0.0f) ? (h1 * rd) : 0.0f;
}

__global__ __launch_bounds__(256) void parzen_kernel(
    const float* __restrict__ img, const float* __restrict__ mask,
    float* __restrict__ out, int V) {
    const int V4 = V >> 2;
    int t = blockIdx.x * blockDim.x + threadIdx.x;
    if (t >= 2 * V4) return;               // B = 2
    int b = (t >= V4) ? 1 : 0;
    int v = (t - b * V4) << 2;

    size_t off0 = (size_t)(b * 2 + 0) * (size_t)V + (size_t)v;  // n = 0
    size_t off1 = (size_t)(b * 2 + 1) * (size_t)V + (size_t)v;  // n = 1

    const float4 X0 = *reinterpret_cast<const float4*>(img  + off0);
    const float4 X1 = *reinterpret_cast<const float4*>(img  + off1);
    const float4 M0 = *reinterpret_cast<const float4*>(mask + off0);
    const float4 M1 = *reinterpret_cast<const float4*>(mask + off1);

    float a0, a1, b0, b1, c0, c1, d0, d1;
    parzen_pair(X0.x, X1.x, M0.x, M1.x, a0, a1);
    parzen_pair(X0.y, X1.y, M0.y, M1.y, b0, b1);
    parzen_pair(X0.z, X1.z, M0.z, M1.z, c0, c1);
    parzen_pair(X0.w, X1.w, M0.w, M1.w, d0, d1);

    f32x4 O0 = {a0, b0, c0, d0};
    f32x4 O1 = {a1, b1, c1, d1};
    __builtin_nontemporal_store(O0, reinterpret_cast<f32x4*>(out + off0));
    __builtin_nontemporal_store(O1, reinterpret_cast<f32x4*>(out + off1));
}

extern "C" void kernel_launch(void* const* d_in, const int* in_sizes, int n_in,
                              void* d_out, int out_size, void* d_ws, size_t ws_size,
                              hipStream_t stream) {
    const float* img  = (const float*)d_in[0];   // [2,2,1,96,96,96] f32
    const float* mask = (const float*)d_in[1];   // [2,2,96,96,96] f32
    float* out = (float*)d_out;                  // [2,2,96,96,96] f32

    int total = in_sizes[0];      // 4*V
    int V = total / 4;            // 884736 (divisible by 4)
    int threads = 2 * (V >> 2);
    int block = 256;
    int grid = (threads + block - 1) / block;
    parzen_kernel<<<grid, block, 0, stream>>>(img, mask, out, V);
}